// Round 8
// baseline (25769.897 us; speedup 1.0000x reference)
//
#include <hip/hip_runtime.h>
#include <math.h>

typedef float f32x4 __attribute__((ext_vector_type(4)));

#define Bb   8
#define Tt   2048
#define Hh   1024
#define NTHR 256
#define NBLK 256
#define BPL  128          // blocks per layer
#define UPL  512          // wave-units per layer (2 cols each)
#define SUBC 4            // sub-counters per (layer,batch)
#define CSTR 16           // dword stride between counter lines (64B)
#define NT   (Tt*Bb)      // total sub-steps
#define R0   4            // fallback ring slots

// ---- primitives (semantics proven rounds 3/5/6/7) ----
__device__ __forceinline__ void llc_load4(f32x4& d, const float* p) {
    asm volatile("global_load_dwordx4 %0, %1, off sc0 sc1" : "=v"(d) : "v"(p));
}
__device__ __forceinline__ void llc_store1(float* p, float v) {
    asm volatile("global_store_dword %0, %1, off sc0 sc1" :: "v"(p), "v"(v) : "memory");
}
__device__ __forceinline__ void vm0() {
    asm volatile("s_waitcnt vmcnt(0)" ::: "memory");
    __builtin_amdgcn_sched_barrier(0);
}
__device__ __forceinline__ float fast_tanh(float s) {
    const float e = __expf(2.f * s);
    return 1.f - 2.f / (e + 1.f);
}
// sum the 4 sub-counter samples held lane-cyclically (lane&3) -> all lanes total
__device__ __forceinline__ unsigned psum(unsigned v) {
    v += __shfl_xor(v, 1, 64);
    v += __shfl_xor(v, 2, 64);
    return v;
}
__device__ __forceinline__ void spin_until(const unsigned* base, int lane, unsigned thr) {
    for (;;) {
        unsigned v = __hip_atomic_load(base + (lane & 3) * CSTR,
                                       __ATOMIC_RELAXED, __HIP_MEMORY_SCOPE_AGENT);
        if (psum(v) >= thr) return;
    }
}

// ==========  primary: batch-pipelined wave-autonomous units  ==========
// unit = 2 output cols of one layer; lane = 16-elem k-slice of each of the
// A-side (x / h0) and H-side (h_prev) dot products. 8 per-batch sub-steps
// per timestep; publish deferred one sub-step so the sc1 store drain
// overlaps compute; dep flags pre-polled one sub-step ahead.
template<int LAY>
__device__ __forceinline__ void run_layer(
    const float* __restrict__ X,  const float* __restrict__ ihw,
    const float* __restrict__ ihb, const float* __restrict__ hhw,
    const float* __restrict__ hhb, float* __restrict__ out,
    float* __restrict__ hist, unsigned* __restrict__ cnt,
    int unit, int lane)
{
    const int colbase = unit * 2;
    const int ks = lane * 16;
    unsigned* cnt0 = cnt;                     // layer-0 counters [8][SUBC]
    unsigned* cOwn = cnt + LAY * 8 * SUBC * CSTR;

    f32x4 wA[2][4], wH[2][4];
    #pragma unroll
    for (int c = 0; c < 2; ++c)
        #pragma unroll
        for (int j = 0; j < 4; ++j) {
            wA[c][j] = *(const f32x4*)&ihw[((size_t)LAY*Hh + colbase + c)*Hh + ks + 4*j];
            wH[c][j] = *(const f32x4*)&hhw[((size_t)LAY*Hh + colbase + c)*Hh + ks + 4*j];
        }
    const float bia0 = ihb[LAY*Hh + colbase]     + hhb[LAY*Hh + colbase];
    const float bia1 = ihb[LAY*Hh + colbase + 1] + hhb[LAY*Hh + colbase + 1];
    const float biam = (lane & 1) ? bia1 : bia0;

    f32x4 ac[4], an[4], hc[4], hn[4];
    unsigned prh = 0, pra = 0, prh_n = 0, pra_n = 0;

    // ---- prologue: stage inputs of sub-step (t=0, b=0) ----
    if (LAY == 0) {
        #pragma unroll
        for (int j = 0; j < 4; ++j)
            ac[j] = *(const f32x4*)&X[(size_t)ks + 4*j];          // X[0][0]
    } else {
        spin_until(cnt0, lane, (unsigned)UPL);                    // c0[0] >= 512
        asm volatile("" ::: "memory");                            // no load hoist
        #pragma unroll
        for (int j = 0; j < 4; ++j)
            ac[j] = *(const f32x4*)&hist[(size_t)ks + 4*j];       // h0[0][0]
    }
    #pragma unroll
    for (int j = 0; j < 4; ++j) hc[j] = f32x4{0.f, 0.f, 0.f, 0.f};

    for (int s = 0; s < NT; ++s) {
        const int t = s >> 3, b = s & 7;

        // -- drain store(s-1) + strays; deferred publish of (s-1) --
        vm0();
        if (s > 0 && lane == 0) {
            const int bp = (s - 1) & 7;
            __hip_atomic_fetch_add(cOwn + (bp*SUBC + (unit & 3))*CSTR, 1u,
                                   __ATOMIC_RELAXED, __HIP_MEMORY_SCOPE_AGENT);
        }

        const int s1 = s + 1;
        if (s1 < NT) {
            const int t1 = s1 >> 3, b1 = s1 & 7;
            // -- check deps of (s+1) (pre-polled last sub-step) --
            if (LAY == 1) {
                const unsigned thrA = (unsigned)(UPL * (t1 + 1));
                if (psum(pra) < thrA) spin_until(cnt0 + b1*SUBC*CSTR, lane, thrA);
            }
            if (t1 > 0) {
                const unsigned thrH = (unsigned)(UPL * t1);
                if (psum(prh) < thrH) spin_until(cOwn + b1*SUBC*CSTR, lane, thrH);
            }
            asm volatile("" ::: "memory");   // forbid hoisting loads above spins
            // -- issue loads for (s+1): plain (L1/L2-cacheable, write-once) --
            const float* ap = (LAY == 0)
                ? (X    + ((size_t)b1*Tt + t1)*Hh + ks)
                : (hist + ((size_t)t1*Bb + b1)*Hh + ks);
            #pragma unroll
            for (int j = 0; j < 4; ++j) an[j] = *(const f32x4*)(ap + 4*j);
            if (t1 > 0) {
                const float* hp = (LAY == 0)
                    ? (hist + ((size_t)(t1-1)*Bb + b1)*Hh + ks)
                    : (out  + ((size_t)b1*Tt + (t1-1))*Hh + ks);
                #pragma unroll
                for (int j = 0; j < 4; ++j) hn[j] = *(const f32x4*)(hp + 4*j);
            } else {
                #pragma unroll
                for (int j = 0; j < 4; ++j) hn[j] = f32x4{0.f, 0.f, 0.f, 0.f};
            }
            // -- issue raw flag polls for (s+2) --
            const int s2 = s + 2;
            if (s2 < NT) {
                const int b2 = s2 & 7;
                prh_n = __hip_atomic_load(cOwn + (b2*SUBC + (lane & 3))*CSTR,
                                          __ATOMIC_RELAXED, __HIP_MEMORY_SCOPE_AGENT);
                if (LAY == 1)
                    pra_n = __hip_atomic_load(cnt0 + (b2*SUBC + (lane & 3))*CSTR,
                                              __ATOMIC_RELAXED, __HIP_MEMORY_SCOPE_AGENT);
            }
        }

        // -- FMA for (t, b): 2 cols x (16 A + 16 H) per lane --
        f32x4 a0 = wA[0][0]*ac[0] + wA[0][1]*ac[1] + wA[0][2]*ac[2] + wA[0][3]*ac[3]
                 + wH[0][0]*hc[0] + wH[0][1]*hc[1] + wH[0][2]*hc[2] + wH[0][3]*hc[3];
        f32x4 a1 = wA[1][0]*ac[0] + wA[1][1]*ac[1] + wA[1][2]*ac[2] + wA[1][3]*ac[3]
                 + wH[1][0]*hc[0] + wH[1][1]*hc[1] + wH[1][2]*hc[2] + wH[1][3]*hc[3];
        const float p0 = (a0[0] + a0[1]) + (a0[2] + a0[3]);
        const float p1 = (a1[0] + a1[1]) + (a1[2] + a1[3]);

        // -- butterfly: lane ends with full sum of col (lane&1) --
        const float pm = (lane & 1) ? p1 : p0;
        const float po = (lane & 1) ? p0 : p1;
        float v = pm + __shfl_xor(po, 1, 64);
        v += __shfl_xor(v, 2, 64);
        v += __shfl_xor(v, 4, 64);
        v += __shfl_xor(v, 8, 64);
        v += __shfl_xor(v, 16, 64);
        v += __shfl_xor(v, 32, 64);

        const float val = fast_tanh(v + biam);

        // -- store (sc1 write-through; publish happens next sub-step) --
        if (lane < 2) {
            float* sp = (LAY == 0)
                ? (hist + ((size_t)t*Bb + b)*Hh + colbase + lane)
                : (out  + ((size_t)b*Tt + t)*Hh + colbase + lane);
            llc_store1(sp, val);
            if (t == Tt - 1)
                out[(size_t)Bb*Tt*Hh + ((size_t)LAY*Bb + b)*Hh + colbase + lane] = val;
        }

        // -- rotate pipeline registers --
        #pragma unroll
        for (int j = 0; j < 4; ++j) { ac[j] = an[j]; hc[j] = hn[j]; }
        prh = prh_n; pra = pra_n;
    }

    // final publish of (Tt-1, 7)
    vm0();
    if (lane == 0)
        __hip_atomic_fetch_add(cOwn + (7*SUBC + (unit & 3))*CSTR, 1u,
                               __ATOMIC_RELAXED, __HIP_MEMORY_SCOPE_AGENT);
}

__global__ __launch_bounds__(NTHR, 1)
void rnn_pipe(const float* __restrict__ X,  const float* __restrict__ ihw,
              const float* __restrict__ ihb, const float* __restrict__ hhw,
              const float* __restrict__ hhb, float* __restrict__ out,
              float* __restrict__ ws)
{
    // flush poison / prior-replay lines from L1/L2 once per run
    __builtin_amdgcn_fence(__ATOMIC_ACQUIRE, "agent");
    const int tid  = threadIdx.x;
    const int lane = tid & 63;
    const int w    = tid >> 6;
    float* hist    = ws;
    unsigned* cnt  = (unsigned*)(ws + (size_t)Tt*Bb*Hh);
    if (blockIdx.x < BPL)
        run_layer<0>(X, ihw, ihb, hhw, hhb, out, hist, cnt,
                     (int)blockIdx.x*4 + w, lane);
    else
        run_layer<1>(X, ihw, ihb, hhw, hhb, out, hist, cnt,
                     ((int)blockIdx.x - BPL)*4 + w, lane);
}

// ==========  fallback: round-5 ring kernel (proven), ws-too-small  =====
#define WPL 128
#define CPW 8
__device__ __forceinline__ void wt_store1(float* p, float v) {
    asm volatile("global_store_dword %0, %1, off sc0 sc1" :: "v"(p), "v"(v) : "memory");
}
__device__ __forceinline__ void wait_ge(const unsigned long long* fq, int tid, unsigned u) {
    unsigned long long a = __hip_atomic_load(fq + tid, __ATOMIC_RELAXED,
                                             __HIP_MEMORY_SCOPE_AGENT);
    bool ok = ((unsigned)a >= u) & ((unsigned)(a >> 32) >= u);
    while (!__all(ok)) {
        __builtin_amdgcn_s_sleep(1);
        a = __hip_atomic_load(fq + tid, __ATOMIC_RELAXED, __HIP_MEMORY_SCOPE_AGENT);
        ok = ((unsigned)a >= u) & ((unsigned)(a >> 32) >= u);
    }
}
#define BUTTERFLY64()                                                      \
    do {                                                                   \
        _Pragma("unroll")                                                  \
        for (int r = 0; r < 6; ++r) {                                      \
            const int bit = (lane >> r) & 1;                               \
            _Pragma("unroll")                                              \
            for (int j = 0; j < (64 >> (r + 1)); ++j) {                    \
                const float send = bit ? vv[2*j]     : vv[2*j + 1];        \
                const float mine = bit ? vv[2*j + 1] : vv[2*j];            \
                vv[j] = mine + __shfl_xor(send, 1 << r, 64);               \
            }                                                              \
        }                                                                  \
    } while (0)

__global__ __launch_bounds__(NTHR, 1)
void rnn_persist5(const float* __restrict__ X, const float* __restrict__ ihw,
                  const float* __restrict__ ihb, const float* __restrict__ hhw,
                  const float* __restrict__ hhb, float* __restrict__ out,
                  float* __restrict__ ws)
{
    __shared__ float red[4*64];
    __shared__ float biasl[CPW];
    const int tid = threadIdx.x;
    const int wg  = blockIdx.x;
    const int lay = (wg >= WPL) ? 1 : 0;
    const int wgl = wg & (WPL-1);
    const int colbase = wgl * CPW;
    const int k0  = tid * 4;
    const int lane = tid & 63;

    float* h0ring = ws;
    float* h1ring = ws + (size_t)R0*Bb*Hh;
    unsigned* flags0 = (unsigned*)(ws + (size_t)(R0+2)*Bb*Hh);
    unsigned* flags1 = flags0 + WPL;
    const unsigned long long* f0q = (const unsigned long long*)flags0;
    const unsigned long long* f1q = (const unsigned long long*)flags1;
    unsigned* myflag = (lay ? flags1 : flags0) + wgl;

    f32x4 wAr[CPW], wBr[CPW];
    #pragma unroll
    for (int c = 0; c < CPW; ++c) {
        const int col = colbase + c;
        wAr[c] = *(const f32x4*)&ihw[((size_t)lay*Hh + col)*Hh + k0];
        wBr[c] = *(const f32x4*)&hhw[((size_t)lay*Hh + col)*Hh + k0];
    }
    if (tid < CPW) {
        const int col = colbase + tid;
        biasl[tid] = ihb[lay*Hh + col] + hhb[lay*Hh + col];
    }
    __syncthreads();

    if (lay == 0) {
        f32x4 xc[Bb];
        #pragma unroll
        for (int b = 0; b < Bb; ++b)
            xc[b] = *(const f32x4*)&X[((size_t)b*Tt)*Hh + k0];
        for (int t = 0; t < Tt; ++t) {
            float acc[CPW][Bb];
            #pragma unroll
            for (int c = 0; c < CPW; ++c) {
                const f32x4 w0 = wAr[c];
                #pragma unroll
                for (int b = 0; b < Bb; ++b) {
                    const f32x4 i0 = xc[b];
                    float a = w0[0]*i0[0]; a += w0[1]*i0[1];
                    a += w0[2]*i0[2]; a += w0[3]*i0[3];
                    acc[c][b] = a;
                }
            }
            if (tid < 64 && t > 0) {
                wait_ge(f0q, tid, (unsigned)t);
                const int tB = t - (R0 - 1);
                if (tB > 0) wait_ge(f1q, tid, (unsigned)tB);
            }
            __syncthreads();
            if (t > 0) {
                const float* hp = h0ring + (size_t)((t-1)&(R0-1))*Bb*Hh;
                f32x4 hv[Bb];
                #pragma unroll
                for (int b = 0; b < Bb; ++b) llc_load4(hv[b], hp + (size_t)b*Hh + k0);
                vm0();
                #pragma unroll
                for (int c = 0; c < CPW; ++c) {
                    const f32x4 w1 = wBr[c];
                    #pragma unroll
                    for (int b = 0; b < Bb; ++b) {
                        const f32x4 i1 = hv[b];
                        acc[c][b] += w1[0]*i1[0]; acc[c][b] += w1[1]*i1[1];
                        acc[c][b] += w1[2]*i1[2]; acc[c][b] += w1[3]*i1[3];
                    }
                }
            }
            float vv[64];
            #pragma unroll
            for (int c = 0; c < CPW; ++c)
                #pragma unroll
                for (int b = 0; b < Bb; ++b) vv[b*8 + c] = acc[c][b];
            BUTTERFLY64();
            red[(tid >> 6)*64 + lane] = vv[0];
            __syncthreads();
            if (tid < 64) {
                const int b = tid >> 3, c = tid & 7;
                const float sfin = red[tid] + red[64 + tid] + red[128 + tid]
                                 + red[192 + tid] + biasl[c];
                const float val = fast_tanh(sfin);
                wt_store1(h0ring + (size_t)(t&(R0-1))*Bb*Hh + (size_t)b*Hh
                          + colbase + c, val);
                asm volatile("s_waitcnt vmcnt(0)" ::: "memory");
                if (tid == 0)
                    __hip_atomic_store(myflag, (unsigned)(t + 1),
                                       __ATOMIC_RELAXED, __HIP_MEMORY_SCOPE_AGENT);
                if (t == Tt-1)
                    out[(size_t)Bb*Tt*Hh + (size_t)b*Hh + colbase + c] = val;
            }
            const int tn = (t + 1 < Tt) ? (t + 1) : t;
            #pragma unroll
            for (int b = 0; b < Bb; ++b)
                xc[b] = *(const f32x4*)&X[((size_t)b*Tt + tn)*Hh + k0];
        }
    } else {
        for (int t = 0; t < Tt; ++t) {
            float acc[CPW][Bb];
            #pragma unroll
            for (int c = 0; c < CPW; ++c)
                #pragma unroll
                for (int b = 0; b < Bb; ++b) acc[c][b] = 0.f;
            if (t > 0) {
                if (tid < 64) wait_ge(f1q, tid, (unsigned)t);
                __syncthreads();
                const float* hp = h1ring + (size_t)((t-1)&1)*Bb*Hh;
                f32x4 hv[Bb];
                #pragma unroll
                for (int b = 0; b < Bb; ++b) llc_load4(hv[b], hp + (size_t)b*Hh + k0);
                vm0();
                #pragma unroll
                for (int c = 0; c < CPW; ++c) {
                    const f32x4 w1 = wBr[c];
                    #pragma unroll
                    for (int b = 0; b < Bb; ++b) {
                        const f32x4 i1 = hv[b];
                        acc[c][b] += w1[0]*i1[0]; acc[c][b] += w1[1]*i1[1];
                        acc[c][b] += w1[2]*i1[2]; acc[c][b] += w1[3]*i1[3];
                    }
                }
            }
            if (tid < 64) wait_ge(f0q, tid, (unsigned)(t + 1));
            __syncthreads();
            {
                const float* apz = h0ring + (size_t)(t&(R0-1))*Bb*Hh;
                f32x4 av[Bb];
                #pragma unroll
                for (int b = 0; b < Bb; ++b) llc_load4(av[b], apz + (size_t)b*Hh + k0);
                vm0();
                #pragma unroll
                for (int c = 0; c < CPW; ++c) {
                    const f32x4 w0 = wAr[c];
                    #pragma unroll
                    for (int b = 0; b < Bb; ++b) {
                        const f32x4 i0 = av[b];
                        acc[c][b] += w0[0]*i0[0]; acc[c][b] += w0[1]*i0[1];
                        acc[c][b] += w0[2]*i0[2]; acc[c][b] += w0[3]*i0[3];
                    }
                }
            }
            float vv[64];
            #pragma unroll
            for (int c = 0; c < CPW; ++c)
                #pragma unroll
                for (int b = 0; b < Bb; ++b) vv[b*8 + c] = acc[c][b];
            BUTTERFLY64();
            red[(tid >> 6)*64 + lane] = vv[0];
            __syncthreads();
            if (tid < 64) {
                const int b = tid >> 3, c = tid & 7;
                const float sfin = red[tid] + red[64 + tid] + red[128 + tid]
                                 + red[192 + tid] + biasl[c];
                const float val = fast_tanh(sfin);
                wt_store1(h1ring + (size_t)(t&1)*Bb*Hh + (size_t)b*Hh
                          + colbase + c, val);
                asm volatile("s_waitcnt vmcnt(0)" ::: "memory");
                if (tid == 0)
                    __hip_atomic_store(myflag, (unsigned)(t + 1),
                                       __ATOMIC_RELAXED, __HIP_MEMORY_SCOPE_AGENT);
                out[((size_t)b*Tt + t)*Hh + colbase + c] = val;
                if (t == Tt-1)
                    out[(size_t)Bb*Tt*Hh + (size_t)(Bb + b)*Hh + colbase + c] = val;
            }
        }
    }
}

extern "C" void kernel_launch(void* const* d_in, const int* in_sizes, int n_in,
                              void* d_out, int out_size, void* d_ws, size_t ws_size,
                              hipStream_t stream) {
    const float* X   = (const float*)d_in[0];
    const float* ihw = (const float*)d_in[1];
    const float* ihb = (const float*)d_in[2];
    const float* hhw = (const float*)d_in[3];
    const float* hhb = (const float*)d_in[4];
    float* outp = (float*)d_out;
    float* wsp  = (float*)d_ws;

    const size_t hist_bytes = (size_t)Tt*Bb*Hh*sizeof(float);        // 67.1 MB
    const size_t cnt_bytes  = (size_t)2*8*SUBC*CSTR*sizeof(unsigned); // 4 KB

    if (ws_size >= hist_bytes + cnt_bytes) {
        hipMemsetAsync((char*)d_ws + hist_bytes, 0, cnt_bytes, stream);
        hipLaunchKernelGGL(rnn_pipe, dim3(NBLK), dim3(NTHR), 0, stream,
                           X, ihw, ihb, hhw, hhb, outp, wsp);
    } else {
        const size_t zero_bytes = (size_t)(R0+2)*Bb*Hh*sizeof(float)
                                + (size_t)2*WPL*sizeof(unsigned);
        hipMemsetAsync(d_ws, 0, zero_bytes, stream);
        hipLaunchKernelGGL(rnn_persist5, dim3(NBLK), dim3(NTHR), 0, stream,
                           X, ihw, ihb, hhw, hhb, outp, wsp);
    }
}

// Round 9
// 9319.096 us; speedup vs baseline: 2.7653x; 2.7653x over previous
//
#include <hip/hip_runtime.h>
#include <math.h>

typedef float f32x4 __attribute__((ext_vector_type(4)));

#define Bb   8
#define Tt   2048
#define Hh   1024
#define NTHR 256
#define NBLK 256
#define WPL  128          // workgroups per layer
#define CPW  8            // columns per workgroup
#define R0   4            // fallback ring slots
#define SENT 2.0f         // sentinel detector: real h in [-1,1]; 0x7F7F7F7F=3.4e38

// ---- primitives (semantics proven rounds 3/5/6/7) ----
__device__ __forceinline__ void llc_load4(f32x4& d, const float* p) {
    asm volatile("global_load_dwordx4 %0, %1, off sc0 sc1" : "=v"(d) : "v"(p));
}
__device__ __forceinline__ void llc_store1(float* p, float v) {
    asm volatile("global_store_dword %0, %1, off sc0 sc1" :: "v"(p), "v"(v) : "memory");
}
__device__ __forceinline__ void vm0() {
    asm volatile("s_waitcnt vmcnt(0)" ::: "memory");
    __builtin_amdgcn_sched_barrier(0);   // rule #18: pin consumers after the wait
}
__device__ __forceinline__ float fast_tanh(float s) {
    const float e = __expf(2.f * s);
    return 1.f - 2.f / (e + 1.f);
}

// data-poll: load 8 b-slices (x4 each) from base+b*stride+k0 until every dword
// is a real value (|x|<=1 written by tanh; sentinel 3.4e38 fails x<2).
// Each iteration reloads all 8; exit values are the valid data.
__device__ __forceinline__ void poll8(f32x4 hv[Bb], const float* base,
                                      size_t stride, int k0) {
    for (;;) {
        #pragma unroll
        for (int b = 0; b < Bb; ++b)
            llc_load4(hv[b], base + (size_t)b*stride + k0);
        vm0();
        bool ok = true;
        #pragma unroll
        for (int b = 0; b < Bb; ++b)
            #pragma unroll
            for (int j = 0; j < 4; ++j) ok &= (hv[b][j] < SENT);
        if (__all(ok)) return;
    }
}

#define BUTTERFLY()                                                        \
    do {                                                                   \
        _Pragma("unroll")                                                  \
        for (int r = 0; r < 6; ++r) {                                      \
            const int bit = (lane >> r) & 1;                               \
            _Pragma("unroll")                                              \
            for (int j = 0; j < (64 >> (r + 1)); ++j) {                    \
                const float send = bit ? v[2*j]     : v[2*j + 1];          \
                const float mine = bit ? v[2*j + 1] : v[2*j];              \
                v[j] = mine + __shfl_xor(send, 1 << r, 64);                \
            }                                                              \
        }                                                                  \
    } while (0)

// ==========  primary: flagless data-polling on write-once history  =======
__global__ __launch_bounds__(NTHR, 1)
void rnn_dpoll(const float* __restrict__ X,  const float* __restrict__ ihw,
               const float* __restrict__ ihb, const float* __restrict__ hhw,
               const float* __restrict__ hhb, float* __restrict__ out,
               float* __restrict__ ws)
{
    __shared__ float red[4*64];
    __shared__ float biasl[CPW];

    const int tid = threadIdx.x;
    const int wg  = blockIdx.x;
    const int lay = (wg >= WPL) ? 1 : 0;
    const int wgl = wg & (WPL-1);
    const int colbase = wgl * CPW;
    const int k0  = tid * 4;
    const int lane = tid & 63;

    float* h0hist = ws;                    // [Tt][Bb][Hh], sentinel-filled

    // persistent weights in registers: 8 cols x 4 k (ih and hh)
    f32x4 wA[CPW], wB[CPW];
    #pragma unroll
    for (int c = 0; c < CPW; ++c) {
        const int col = colbase + c;
        wA[c] = *(const f32x4*)&ihw[((size_t)lay*Hh + col)*Hh + k0];
        wB[c] = *(const f32x4*)&hhw[((size_t)lay*Hh + col)*Hh + k0];
    }
    if (tid < CPW) {
        const int col = colbase + tid;
        biasl[tid] = ihb[lay*Hh + col] + hhb[lay*Hh + col];
    }
    __syncthreads();

    if (lay == 0) {
        // ---------------- layer 0 ----------------
        f32x4 xc[Bb];
        #pragma unroll
        for (int b = 0; b < Bb; ++b)
            xc[b] = *(const f32x4*)&X[((size_t)b*Tt)*Hh + k0];

        for (int t = 0; t < Tt; ++t) {
            // 1) ih partials first (independent work while producers finish)
            float acc[CPW][Bb];
            #pragma unroll
            for (int c = 0; c < CPW; ++c) {
                const f32x4 w0 = wA[c];
                #pragma unroll
                for (int b = 0; b < Bb; ++b) {
                    const f32x4 i0 = xc[b];
                    float a = w0[0]*i0[0]; a += w0[1]*i0[1];
                    a += w0[2]*i0[2]; a += w0[3]*i0[3];
                    acc[c][b] = a;
                }
            }

            // 2) hh half: data-poll h0(t-1), per-thread, no barrier
            if (t > 0) {
                f32x4 hv[Bb];
                poll8(hv, h0hist + (size_t)(t-1)*Bb*Hh, Hh, k0);
                #pragma unroll
                for (int c = 0; c < CPW; ++c) {
                    const f32x4 w1 = wB[c];
                    #pragma unroll
                    for (int b = 0; b < Bb; ++b) {
                        const f32x4 i1 = hv[b];
                        acc[c][b] += w1[0]*i1[0]; acc[c][b] += w1[1]*i1[1];
                        acc[c][b] += w1[2]*i1[2]; acc[c][b] += w1[3]*i1[3];
                    }
                }
            }

            // 3) butterfly: lane ends with output o = lane (o = b*8 + c)
            float v[64];
            #pragma unroll
            for (int c = 0; c < CPW; ++c)
                #pragma unroll
                for (int b = 0; b < Bb; ++b) v[b*8 + c] = acc[c][b];
            BUTTERFLY();
            red[(tid >> 6)*64 + lane] = v[0];
            __syncthreads();

            // 4) combine + tanh + fire-and-forget publish (data IS the flag)
            if (tid < 64) {
                const int b = tid >> 3, c = tid & 7;
                const float s = red[tid] + red[64 + tid] + red[128 + tid]
                              + red[192 + tid] + biasl[c];
                const float val = fast_tanh(s);
                llc_store1(h0hist + (size_t)t*Bb*Hh + (size_t)b*Hh + colbase + c, val);
                if (t == Tt-1)
                    out[(size_t)Bb*Tt*Hh + (size_t)b*Hh + colbase + c] = val; // h_T[0]
            }

            // 5) X prefetch for t+1
            const int tn = (t + 1 < Tt) ? (t + 1) : t;
            #pragma unroll
            for (int b = 0; b < Bb; ++b)
                xc[b] = *(const f32x4*)&X[((size_t)b*Tt + tn)*Hh + k0];

            __syncthreads();   // red WAR before next iteration
        }
    } else {
        // ---------------- layer 1 (h1 history IS ys in d_out) ----------------
        for (int t = 0; t < Tt; ++t) {
            float acc[CPW][Bb];
            #pragma unroll
            for (int c = 0; c < CPW; ++c)
                #pragma unroll
                for (int b = 0; b < Bb; ++b) acc[c][b] = 0.f;

            // stage 1: hh half — data-poll ys(t-1) (self-layer history)
            if (t > 0) {
                f32x4 hv[Bb];
                poll8(hv, out + (size_t)(t-1)*Hh, (size_t)Tt*Hh, k0);
                #pragma unroll
                for (int c = 0; c < CPW; ++c) {
                    const f32x4 w1 = wB[c];
                    #pragma unroll
                    for (int b = 0; b < Bb; ++b) {
                        const f32x4 i1 = hv[b];
                        acc[c][b] += w1[0]*i1[0]; acc[c][b] += w1[1]*i1[1];
                        acc[c][b] += w1[2]*i1[2]; acc[c][b] += w1[3]*i1[3];
                    }
                }
            }

            // stage 2: ih half — data-poll h0(t)
            {
                f32x4 av[Bb];
                poll8(av, h0hist + (size_t)t*Bb*Hh, Hh, k0);
                #pragma unroll
                for (int c = 0; c < CPW; ++c) {
                    const f32x4 w0 = wA[c];
                    #pragma unroll
                    for (int b = 0; b < Bb; ++b) {
                        const f32x4 i0 = av[b];
                        acc[c][b] += w0[0]*i0[0]; acc[c][b] += w0[1]*i0[1];
                        acc[c][b] += w0[2]*i0[2]; acc[c][b] += w0[3]*i0[3];
                    }
                }
            }

            // butterfly
            float v[64];
            #pragma unroll
            for (int c = 0; c < CPW; ++c)
                #pragma unroll
                for (int b = 0; b < Bb; ++b) v[b*8 + c] = acc[c][b];
            BUTTERFLY();
            red[(tid >> 6)*64 + lane] = v[0];
            __syncthreads();

            // combine + tanh; the ys store IS the publish
            if (tid < 64) {
                const int b = tid >> 3, c = tid & 7;
                const float s = red[tid] + red[64 + tid] + red[128 + tid]
                              + red[192 + tid] + biasl[c];
                const float val = fast_tanh(s);
                llc_store1(out + ((size_t)b*Tt + t)*Hh + colbase + c, val);
                if (t == Tt-1)
                    out[(size_t)Bb*Tt*Hh + (size_t)(Bb + b)*Hh + colbase + c] = val; // h_T[1]
            }
            __syncthreads();   // red WAR
        }
    }
}

// ==========  fallback: round-5 ring kernel (proven), ws-too-small  =====
__device__ __forceinline__ void wait_ge(const unsigned long long* fq, int tid, unsigned u) {
    unsigned long long a = __hip_atomic_load(fq + tid, __ATOMIC_RELAXED,
                                             __HIP_MEMORY_SCOPE_AGENT);
    bool ok = ((unsigned)a >= u) & ((unsigned)(a >> 32) >= u);
    while (!__all(ok)) {
        __builtin_amdgcn_s_sleep(1);
        a = __hip_atomic_load(fq + tid, __ATOMIC_RELAXED, __HIP_MEMORY_SCOPE_AGENT);
        ok = ((unsigned)a >= u) & ((unsigned)(a >> 32) >= u);
    }
}

__global__ __launch_bounds__(NTHR, 1)
void rnn_persist5(const float* __restrict__ X, const float* __restrict__ ihw,
                  const float* __restrict__ ihb, const float* __restrict__ hhw,
                  const float* __restrict__ hhb, float* __restrict__ out,
                  float* __restrict__ ws)
{
    __shared__ float red[4*64];
    __shared__ float biasl[CPW];
    const int tid = threadIdx.x;
    const int wg  = blockIdx.x;
    const int lay = (wg >= WPL) ? 1 : 0;
    const int wgl = wg & (WPL-1);
    const int colbase = wgl * CPW;
    const int k0  = tid * 4;
    const int lane = tid & 63;

    float* h0ring = ws;
    float* h1ring = ws + (size_t)R0*Bb*Hh;
    unsigned* flags0 = (unsigned*)(ws + (size_t)(R0+2)*Bb*Hh);
    unsigned* flags1 = flags0 + WPL;
    const unsigned long long* f0q = (const unsigned long long*)flags0;
    const unsigned long long* f1q = (const unsigned long long*)flags1;
    unsigned* myflag = (lay ? flags1 : flags0) + wgl;

    f32x4 wAr[CPW], wBr[CPW];
    #pragma unroll
    for (int c = 0; c < CPW; ++c) {
        const int col = colbase + c;
        wAr[c] = *(const f32x4*)&ihw[((size_t)lay*Hh + col)*Hh + k0];
        wBr[c] = *(const f32x4*)&hhw[((size_t)lay*Hh + col)*Hh + k0];
    }
    if (tid < CPW) {
        const int col = colbase + tid;
        biasl[tid] = ihb[lay*Hh + col] + hhb[lay*Hh + col];
    }
    __syncthreads();

    if (lay == 0) {
        f32x4 xc[Bb];
        #pragma unroll
        for (int b = 0; b < Bb; ++b)
            xc[b] = *(const f32x4*)&X[((size_t)b*Tt)*Hh + k0];
        for (int t = 0; t < Tt; ++t) {
            float acc[CPW][Bb];
            #pragma unroll
            for (int c = 0; c < CPW; ++c) {
                const f32x4 w0 = wAr[c];
                #pragma unroll
                for (int b = 0; b < Bb; ++b) {
                    const f32x4 i0 = xc[b];
                    float a = w0[0]*i0[0]; a += w0[1]*i0[1];
                    a += w0[2]*i0[2]; a += w0[3]*i0[3];
                    acc[c][b] = a;
                }
            }
            if (tid < 64 && t > 0) {
                wait_ge(f0q, tid, (unsigned)t);
                const int tB = t - (R0 - 1);
                if (tB > 0) wait_ge(f1q, tid, (unsigned)tB);
            }
            __syncthreads();
            if (t > 0) {
                const float* hp = h0ring + (size_t)((t-1)&(R0-1))*Bb*Hh;
                f32x4 hv[Bb];
                #pragma unroll
                for (int b = 0; b < Bb; ++b) llc_load4(hv[b], hp + (size_t)b*Hh + k0);
                vm0();
                #pragma unroll
                for (int c = 0; c < CPW; ++c) {
                    const f32x4 w1 = wBr[c];
                    #pragma unroll
                    for (int b = 0; b < Bb; ++b) {
                        const f32x4 i1 = hv[b];
                        acc[c][b] += w1[0]*i1[0]; acc[c][b] += w1[1]*i1[1];
                        acc[c][b] += w1[2]*i1[2]; acc[c][b] += w1[3]*i1[3];
                    }
                }
            }
            float v[64];
            #pragma unroll
            for (int c = 0; c < CPW; ++c)
                #pragma unroll
                for (int b = 0; b < Bb; ++b) v[b*8 + c] = acc[c][b];
            BUTTERFLY();
            red[(tid >> 6)*64 + lane] = v[0];
            __syncthreads();
            if (tid < 64) {
                const int b = tid >> 3, c = tid & 7;
                const float sfin = red[tid] + red[64 + tid] + red[128 + tid]
                                 + red[192 + tid] + biasl[c];
                const float val = fast_tanh(sfin);
                llc_store1(h0ring + (size_t)(t&(R0-1))*Bb*Hh + (size_t)b*Hh
                           + colbase + c, val);
                asm volatile("s_waitcnt vmcnt(0)" ::: "memory");
                if (tid == 0)
                    __hip_atomic_store(myflag, (unsigned)(t + 1),
                                       __ATOMIC_RELAXED, __HIP_MEMORY_SCOPE_AGENT);
                if (t == Tt-1)
                    out[(size_t)Bb*Tt*Hh + (size_t)b*Hh + colbase + c] = val;
            }
            const int tn = (t + 1 < Tt) ? (t + 1) : t;
            #pragma unroll
            for (int b = 0; b < Bb; ++b)
                xc[b] = *(const f32x4*)&X[((size_t)b*Tt + tn)*Hh + k0];
        }
    } else {
        for (int t = 0; t < Tt; ++t) {
            float acc[CPW][Bb];
            #pragma unroll
            for (int c = 0; c < CPW; ++c)
                #pragma unroll
                for (int b = 0; b < Bb; ++b) acc[c][b] = 0.f;
            if (t > 0) {
                if (tid < 64) wait_ge(f1q, tid, (unsigned)t);
                __syncthreads();
                const float* hp = h1ring + (size_t)((t-1)&1)*Bb*Hh;
                f32x4 hv[Bb];
                #pragma unroll
                for (int b = 0; b < Bb; ++b) llc_load4(hv[b], hp + (size_t)b*Hh + k0);
                vm0();
                #pragma unroll
                for (int c = 0; c < CPW; ++c) {
                    const f32x4 w1 = wBr[c];
                    #pragma unroll
                    for (int b = 0; b < Bb; ++b) {
                        const f32x4 i1 = hv[b];
                        acc[c][b] += w1[0]*i1[0]; acc[c][b] += w1[1]*i1[1];
                        acc[c][b] += w1[2]*i1[2]; acc[c][b] += w1[3]*i1[3];
                    }
                }
            }
            if (tid < 64) wait_ge(f0q, tid, (unsigned)(t + 1));
            __syncthreads();
            {
                const float* apz = h0ring + (size_t)(t&(R0-1))*Bb*Hh;
                f32x4 av[Bb];
                #pragma unroll
                for (int b = 0; b < Bb; ++b) llc_load4(av[b], apz + (size_t)b*Hh + k0);
                vm0();
                #pragma unroll
                for (int c = 0; c < CPW; ++c) {
                    const f32x4 w0 = wAr[c];
                    #pragma unroll
                    for (int b = 0; b < Bb; ++b) {
                        const f32x4 i0 = av[b];
                        acc[c][b] += w0[0]*i0[0]; acc[c][b] += w0[1]*i0[1];
                        acc[c][b] += w0[2]*i0[2]; acc[c][b] += w0[3]*i0[3];
                    }
                }
            }
            float v[64];
            #pragma unroll
            for (int c = 0; c < CPW; ++c)
                #pragma unroll
                for (int b = 0; b < Bb; ++b) v[b*8 + c] = acc[c][b];
            BUTTERFLY();
            red[(tid >> 6)*64 + lane] = v[0];
            __syncthreads();
            if (tid < 64) {
                const int b = tid >> 3, c = tid & 7;
                const float sfin = red[tid] + red[64 + tid] + red[128 + tid]
                                 + red[192 + tid] + biasl[c];
                const float val = fast_tanh(sfin);
                llc_store1(h1ring + (size_t)(t&1)*Bb*Hh + (size_t)b*Hh
                           + colbase + c, val);
                asm volatile("s_waitcnt vmcnt(0)" ::: "memory");
                if (tid == 0)
                    __hip_atomic_store(myflag, (unsigned)(t + 1),
                                       __ATOMIC_RELAXED, __HIP_MEMORY_SCOPE_AGENT);
                out[((size_t)b*Tt + t)*Hh + colbase + c] = val;
                if (t == Tt-1)
                    out[(size_t)Bb*Tt*Hh + (size_t)(Bb + b)*Hh + colbase + c] = val;
            }
        }
    }
}

extern "C" void kernel_launch(void* const* d_in, const int* in_sizes, int n_in,
                              void* d_out, int out_size, void* d_ws, size_t ws_size,
                              hipStream_t stream) {
    const float* X   = (const float*)d_in[0];
    const float* ihw = (const float*)d_in[1];
    const float* ihb = (const float*)d_in[2];
    const float* hhw = (const float*)d_in[3];
    const float* hhb = (const float*)d_in[4];
    float* outp = (float*)d_out;
    float* wsp  = (float*)d_ws;

    const size_t hist_bytes = (size_t)Tt*Bb*Hh*sizeof(float);   // 67.1 MB

    if (ws_size >= hist_bytes) {
        // sentinel-fill the poll targets (0x7F7F7F7F = 3.39e38 > SENT):
        // h0 history in ws, and d_out (ys is layer-1's polled history).
        hipMemsetAsync(d_ws, 0x7F, hist_bytes, stream);
        hipMemsetAsync(d_out, 0x7F, (size_t)out_size*sizeof(float), stream);
        hipLaunchKernelGGL(rnn_dpoll, dim3(NBLK), dim3(NTHR), 0, stream,
                           X, ihw, ihb, hhw, hhb, outp, wsp);
    } else {
        const size_t zero_bytes = (size_t)(R0+2)*Bb*Hh*sizeof(float)
                                + (size_t)2*WPL*sizeof(unsigned);
        hipMemsetAsync(d_ws, 0, zero_bytes, stream);
        hipLaunchKernelGGL(rnn_persist5, dim3(NBLK), dim3(NTHR), 0, stream,
                           X, ihw, ihb, hhw, hhb, outp, wsp);
    }
}